// Round 11
// baseline (203.005 us; speedup 1.0000x reference)
//
#include <hip/hip_runtime.h>
#include <hip/hip_bf16.h>

// ---------- constants ----------
#define M_ROWS   11520          // b*n = 2*5760
#define D_IN     512
#define HD       1960
#define HDP      2048           // padded N for GEMM1 tiles
#define CPAD     52             // per-cch padded patch count (49 -> 52)
#define K2       2080           // 40*52, GEMM2 logical K
#define K2P      2112           // K2 padded to 64 (BK=64 -> 33 steps); tails zeroed
#define B2C      16
#define NVECS    720            // 20*36
#define LH       20
#define LW       36
#define HH       60
#define WW       108
#define CCH      40             // 1960/49

using bf16x8 = __attribute__((ext_vector_type(8))) short;
using f32x4  = __attribute__((ext_vector_type(4))) float;
using f4     = __attribute__((ext_vector_type(4))) float;
using su4    = __attribute__((ext_vector_type(4))) unsigned short;

__device__ __forceinline__ float bf2f(unsigned short u) {
    unsigned int x = ((unsigned int)u) << 16;
    return __builtin_bit_cast(float, x);
}
__device__ __forceinline__ unsigned short f2bf(float f) {
    unsigned int x = __builtin_bit_cast(unsigned int, f);
    unsigned int r = (x + 0x7fffu + ((x >> 16) & 1u)) >> 16;
    return (unsigned short)r;
}

// async global->LDS, 16 bytes per lane (global_load_lds_dwordx4)
__device__ __forceinline__ void gl_lds16(const unsigned short* g, unsigned short* l) {
    __builtin_amdgcn_global_load_lds(
        (const __attribute__((address_space(1))) unsigned int*)g,
        (__attribute__((address_space(3))) unsigned int*)l, 16, 0, 0);
}

// ---------- prep: conv x -> bf16 | pack W1t | pack W2t (52-relabel, K2P stride) ----------
__global__ __launch_bounds__(256) void prep(
    const float* __restrict__ x, const float* __restrict__ W1, const float* __restrict__ W2,
    unsigned short* __restrict__ xb, unsigned short* __restrict__ w1t,
    unsigned short* __restrict__ w2t)
{
    __shared__ unsigned short tile[32][33];
    int b = blockIdx.x, t = threadIdx.x;
    if (b < 5760) {                               // x (f32) -> xb (bf16), 4/thread
        int i = b * 256 + t;
        f4 v = ((const f4*)x)[i];
        su4 o;
        o.x = f2bf(v.x); o.y = f2bf(v.y); o.z = f2bf(v.z); o.w = f2bf(v.w);
        ((su4*)xb)[i] = o;
        return;
    }
    int tx = t & 31, ty = t >> 5;                 // ty in [0,8)
    if (b < 6784) {                               // W1t[n*512+k] = W1[k*1960+n]
        int blk = b - 5760;
        int kt = blk & 15, nt = blk >> 4;
        int k0 = kt * 32, n0 = nt * 32;
#pragma unroll
        for (int p = 0; p < 4; p++) {
            int k = k0 + ty + p * 8;
            int n = n0 + tx;
            tile[ty + p * 8][tx] = (n < HD) ? f2bf(W1[k * HD + n]) : (unsigned short)0;
        }
        __syncthreads();
#pragma unroll
        for (int p = 0; p < 4; p++) {
            int n = n0 + ty + p * 8;
            int k = k0 + tx;
            w1t[n * 512 + k] = tile[tx][ty + p * 8];
        }
    } else {                                      // W2t[n*K2P + cch*52+kk] = W2[(cch*49+kk)*512+n]
        int blk = b - 6784;                       // 62 kt x 16 nt
        int kt = blk % 62, nt = blk / 62;
        int k0 = kt * 32, n0 = nt * 32;
        if (kt == 0) {                            // zero 52-pad holes + K2P tail once per n-tile
            for (int i = t; i < 32 * CCH * 3; i += 256) {
                int nn = n0 + (i & 31);
                int cc = (i >> 5) / 3, p = (i >> 5) % 3;
                w2t[nn * K2P + cc * CPAD + 49 + p] = 0;
            }
            if (t < 256) {                        // 32 rows x 8 su4 = 256: tail [2080,2112)
                su4 z = {};
                int nn = n0 + (t >> 3), e = t & 7;
                *(su4*)(w2t + (size_t)nn * K2P + 2080 + e * 4) = z;
            }
        }
#pragma unroll
        for (int p = 0; p < 4; p++) {
            int k = k0 + ty + p * 8;
            int n = n0 + tx;
            tile[ty + p * 8][tx] = (k < HD) ? f2bf(W2[k * 512 + n]) : (unsigned short)0;
        }
        __syncthreads();
#pragma unroll
        for (int p = 0; p < 4; p++) {
            int n = n0 + ty + p * 8;
            int k = k0 + tx;
            if (k < HD) {
                int cch = k / 49, kk = k - cch * 49;
                w2t[n * K2P + cch * CPAD + kk] = tile[tx][ty + p * 8];
            }
        }
    }
}

// ---------- GEMM1: BK=64 (two 32-col sub-tiles), 8 waves, 128x128, 1440 blocks ----------
// R10 post-mortem: BK=64 amortization PROVEN on gemm2 (48.3 -> ~34us; occupancy/
// vmcnt/depth levers all null before it). Same port here: NT 16->8, barriers
// 32->16, 16 MFMA/wave per barrier-pair. Two 32-col sub-tiles per buffer =
// identical addressing algebra to the verified kernels. Staging uniform:
// 4 gl_lds16/thread/iter (A 2 + B 2), steady-state vmcnt(4).
// LDS 2x(16+16)=64KB -> 2 blocks/CU (16 waves/CU; R9 proved this suffices).
__global__ __launch_bounds__(512) void gemm1_blk(
    const unsigned short* __restrict__ A,
    const unsigned short* __restrict__ Bt,
    const float* __restrict__ bias,
    unsigned short* __restrict__ h_blk)
{
    __shared__ unsigned short sA[2 * 2 * 128 * 32];   // 2 buf x 2 sub x 8KB = 32KB
    __shared__ unsigned short sB[2 * 2 * 128 * 32];   // 32KB (64KB total)
    const int lda = D_IN, ldb = D_IN;
    const int NT = D_IN / 64;                     // 8 K-steps of 64

    int g = (blockIdx.x & 7) * 180 + (blockIdx.x >> 3);   // 1440 blocks, chunk=180
    int bx = g & 15, by = g >> 4;
    int t    = threadIdx.x;                       // 0..511
    int w    = t >> 6;                            // 0..7
    int lane = t & 63;
    int quad = lane >> 4;
    int l16  = lane & 15;
    int row0 = by * 128, col0 = bx * 128;
    int wr = (w >> 2) * 64;                       // 0 or 64
    int wc = (w & 3) * 32;                        // 0,32,64,96

    int srow = t >> 2;                            // 0..127
    int qb = ((t & 3) - ((srow >> 1) & 3)) & 3;   // global 16B-block this thread stages
    const unsigned short* Ag = A  + (size_t)(row0 + srow) * lda + qb * 8;
    const unsigned short* Bg = Bt + (size_t)(col0 + srow) * ldb + qb * 8;
    unsigned short* lA = sA + t * 8;              // + buf*8192 + sub*4096
    unsigned short* lB = sB + t * 8;

    int xq = (quad + ((l16 >> 1) & 3)) & 3;       // swizzled read slot

    f32x4 acc[4][2] = {};

    // prologue: stage K-step 0 (k=0..63) into buf0 (4 ops/thread)
    gl_lds16(Ag,      lA);
    gl_lds16(Ag + 32, lA + 4096);
    gl_lds16(Bg,      lB);
    gl_lds16(Bg + 32, lB + 4096);

#pragma unroll
    for (int it = 0; it < NT; ++it) {
        const int cur = it & 1, nxt = cur ^ 1;
        if (it + 1 < NT) {
            const int k0n = (it + 1) * 64;
            gl_lds16(Ag + k0n,      lA + nxt * 8192);
            gl_lds16(Ag + k0n + 32, lA + nxt * 8192 + 4096);
            gl_lds16(Bg + k0n,      lB + nxt * 8192);
            gl_lds16(Bg + k0n + 32, lB + nxt * 8192 + 4096);
            asm volatile("s_waitcnt vmcnt(4)" ::: "memory");  // cur's 4 done; nxt's 4 in flight
        } else {
            asm volatile("s_waitcnt vmcnt(0)" ::: "memory");
        }
        __builtin_amdgcn_s_barrier();             // all waves: cur staged
        asm volatile("" ::: "memory");            // no LDS reads hoisted above barrier

        const unsigned short* bA = sA + cur * 8192;
        const unsigned short* bB = sB + cur * 8192;

#pragma unroll
        for (int s = 0; s < 2; s++) {
            bf16x8 a[4], bfr[2];
#pragma unroll
            for (int i = 0; i < 4; i++)
                a[i] = *(const bf16x8*)(bA + s * 4096 + (wr + i * 16 + l16) * 32 + xq * 8);
#pragma unroll
            for (int j = 0; j < 2; j++)
                bfr[j] = *(const bf16x8*)(bB + s * 4096 + (wc + j * 16 + l16) * 32 + xq * 8);
#pragma unroll
            for (int i = 0; i < 4; i++)
#pragma unroll
                for (int j = 0; j < 2; j++)
                    acc[i][j] = __builtin_amdgcn_mfma_f32_16x16x32_bf16(a[i], bfr[j], acc[i][j], 0, 0, 0);
        }
        asm volatile("" ::: "memory");
        __builtin_amdgcn_s_barrier();             // all waves done reading cur
        asm volatile("" ::: "memory");
    }

    // row terms: addr = b2*1497600 + cch*37440 + sp*52 + kk
    int rowterm[16];
#pragma unroll
    for (int i = 0; i < 4; i++)
#pragma unroll
        for (int r = 0; r < 4; r++) {
            int row = row0 + wr + i * 16 + quad * 4 + r;
            int bb = row / NVECS;
            int sp = row - bb * NVECS;
            rowterm[i * 4 + r] = bb * (CCH * NVECS * CPAD) + sp * CPAD;
        }

#pragma unroll
    for (int j = 0; j < 2; j++) {
        int col = col0 + wc + j * 16 + l16;       // natural: col = cch*49 + kk
        if (col < HD) {
            int cch = col / 49, kk = col - cch * 49;
            int colterm = cch * (NVECS * CPAD) + kk;
            float bv = bias[col];
#pragma unroll
            for (int i = 0; i < 4; i++)
#pragma unroll
                for (int r = 0; r < 4; r++)
                    h_blk[(size_t)rowterm[i * 4 + r] + colterm] = f2bf(acc[i][j][r] + bv);
        }
    }

    // zero pad holes (kk=49..51) of every cch-row this tile covers -> dense sectors
    int cch0 = col0 / 49;
    int cch1 = (col0 + 127) / 49; if (cch1 > CCH - 1) cch1 = CCH - 1;
    int ncch = cch1 - cch0 + 1;
    if (wc == 0 && l16 < 3 * ncch) {
        int c = l16 / 3, p = l16 - c * 3;
        int padcol = (cch0 + c) * (NVECS * CPAD) + 49 + p;
#pragma unroll
        for (int i = 0; i < 4; i++)
#pragma unroll
            for (int r = 0; r < 4; r++)
                h_blk[(size_t)rowterm[i * 4 + r] + padcol] = 0;
    }
}

// ---------- fused fold+norm+relu+unfold, VALU-lean mapping (uf stride K2P) ----------
__global__ __launch_bounds__(256) void fold_unfold(
    const unsigned short* __restrict__ h_blk,
    unsigned short* __restrict__ uf)
{
    __shared__ unsigned short h_lds[12 * 36 * CPAD];  // 44,928 B
    __shared__ unsigned short y_lds[33 * WW];         //  7,128 B
    int bid  = blockIdx.x;                            // 16*40*2 = 1280
    int half = bid & 1;
    int cch  = (bid >> 1) % CCH;
    int b2   = bid / (CCH * 2);
    int tid  = threadIdx.x;

    int lh_base = half ? 8 : 0;
    int y0 = half ? 27 : 0;
    int ny = half ? 33 : 31;

    const su4* hsrc = (const su4*)(h_blk +
        ((size_t)(b2 * CCH + cch) * NVECS + lh_base * 36) * CPAD);
    su4* hd = (su4*)h_lds;
    for (int i = tid; i < 12 * 36 * CPAD / 4; i += 256)
        hd[i] = hsrc[i];
    __syncthreads();

    // ---- fold+norm+relu: thread owns column c; rows strided by 2 ----
    if (tid < 216) {
        int c  = tid % 108;
        int rr = tid / 108;                       // 0 or 1
        int cp  = c + 3;
        int q2  = cp / 3, rem2 = cp - q2 * 3;
        bool cv0 = (q2 <= 35);
        bool cv2 = (rem2 == 0) & (q2 >= 2);
        int n2  = 1 + (int)cv0 + (int)cv2;
        float rn2 = (n2 == 3) ? (1.0f / 3.0f) : (n2 == 2 ? 0.5f : 1.0f);
        int ca0 = q2 * CPAD + rem2;               // lw0 col offset (valid iff cv0)
        int ca1 = (q2 - 1) * CPAD + rem2 + 3;     // lw1 (always valid)
        int ca2 = (q2 - 2) * CPAD + rem2 + 6;     // lw2 (valid iff cv2)
        for (; rr < ny; rr += 2) {
            int r  = y0 + rr;
            int rp = r + 3;
            int q1 = rp / 3, rem1 = rp - q1 * 3;
            bool rv0 = (q1 <= 19);
            bool rv2 = (rem1 == 0) & (q1 >= 2);
            int n1 = 1 + (int)rv0 + (int)rv2;
            float rn1 = (n1 == 3) ? (1.0f / 3.0f) : (n1 == 2 ? 0.5f : 1.0f);
            int ra0 = (q1 - lh_base) * (36 * CPAD) + rem1 * 7;   // sl0 row base
            int ra1 = ra0 - 36 * CPAD + 21;                      // sl1
            int ra2 = ra0 - 2 * (36 * CPAD) + 42;                // sl2
            float s = 0.0f;
#define FT(vr, ra, vc, ca) {                                   \
            bool vv = (vr) & (vc);                             \
            int ad = vv ? ((ra) + (ca)) : 0;                   \
            float val = bf2f(h_lds[ad]);                       \
            s += vv ? val : 0.0f; }
            FT(rv0,  ra0, cv0,  ca0)
            FT(rv0,  ra0, true, ca1)
            FT(rv0,  ra0, cv2,  ca2)
            FT(true, ra1, cv0,  ca0)
            FT(true, ra1, true, ca1)
            FT(true, ra1, cv2,  ca2)
            FT(rv2,  ra2, cv0,  ca0)
            FT(rv2,  ra2, true, ca1)
            FT(rv2,  ra2, cv2,  ca2)
#undef FT
            y_lds[rr * WW + c] = f2bf(fmaxf(s * rn1 * rn2, 0.0f));
        }
    }
    __syncthreads();

    // ---- unfold: thread owns quad q (j0=4q); rows strided by 19 ----
    if (tid < 247) {
        int q  = tid % 13;
        int ri = tid / 13;                        // 0..18
        int j0 = q * 4;
        int lh0 = 10 * half;
        int k1c[4], k2c[4];
        bool jv[4];
#pragma unroll
        for (int e = 0; e < 4; e++) {
            int j = j0 + e;
            jv[e] = (j < 49);
            int k1 = j / 7;
            k1c[e] = k1;
            k2c[e] = j - k1 * 7;
        }
        int lh = lh0, lw = ri;                    // ri < 19 < 36
        for (int rcur = ri; rcur < 360; rcur += 19) {
            int rb = 3 * lh - 3, cb = 3 * lw - 3;
            su4 o;
#pragma unroll
            for (int e = 0; e < 4; e++) {
                unsigned short val = 0;
                if (jv[e]) {
                    int r = rb + k1c[e], cc = cb + k2c[e];
                    if ((unsigned)r < (unsigned)HH && (unsigned)cc < (unsigned)WW)
                        val = y_lds[(r - y0) * WW + cc];
                }
                ((unsigned short*)&o)[e] = val;
            }
            int row = b2 * NVECS + lh * 36 + lw;
            *(su4*)(uf + (size_t)row * K2P + cch * CPAD + j0) = o;
            lw += 19;
            if (lw >= 36) { lw -= 36; lh++; }
        }
    }

    // ---- zero uf K2P tail [2080,2112) for this (b2,half)'s 360 rows (cch==0 blocks) ----
    if (cch == 0) {
        su4 z = {};
        size_t base = (size_t)(b2 * NVECS + (10 * half) * 36) * K2P + 2080;
        for (int i = tid; i < 360 * 8; i += 256) {
            int rr = i >> 3, e = i & 7;
            *(su4*)(uf + base + (size_t)rr * K2P + e * 4) = z;
        }
    }
}

// ---------- GEMM2: BK=64 (two 32-col sub-tiles), 8 waves, 128x64, 720 blocks ----------
__global__ __launch_bounds__(512) void gemm2(
    const unsigned short* __restrict__ A,
    const unsigned short* __restrict__ Bt,
    const float* __restrict__ bias,
    float* __restrict__ C)
{
    __shared__ unsigned short sA[2 * 2 * 128 * 32];   // 2 buf x 2 sub x 8KB = 32KB
    __shared__ unsigned short sB[2 * 2 * 64 * 32];    // 2 buf x 2 sub x 4KB = 16KB
    const int lda = K2P, ldb = K2P, ldc = D_IN;
    const int NT = K2P / 64;                      // 33 K-steps of 64

    int g = (blockIdx.x & 7) * 90 + (blockIdx.x >> 3);    // 720 blocks, chunk=90
    int bx = g & 7, by = g >> 3;                          // 8 col-tiles of 64, 90 row-tiles
    int t    = threadIdx.x;                       // 0..511
    int w    = t >> 6;                            // 0..7
    int lane = t & 63;
    int quad = lane >> 4;
    int l16  = lane & 15;
    int row0 = by * 128, col0 = bx * 64;
    int wr = (w >> 1) * 32;                       // 0,32,64,96
    int wc = (w & 1) * 32;                        // 0,32

    bool stager = (t < 256);                      // B stagers (wave-uniform)
    int srow  = t >> 2;                           // 0..127 (A rows)
    int srowB = srow & 63;                        // 0..63  (B rows, t<256 only)
    int qb  = ((t & 3) - ((srow  >> 1) & 3)) & 3;
    int qbB = ((t & 3) - ((srowB >> 1) & 3)) & 3;
    const unsigned short* Ag = A  + (size_t)(row0 + srow)  * lda + qb  * 8;
    const unsigned short* Bg = Bt + (size_t)(col0 + srowB) * ldb + qbB * 8;
    unsigned short* lA = sA + t * 8;              // + buf*8192 + sub*4096
    unsigned short* lB = sB + t * 8;              // + buf*4096 + sub*2048 (t<256)

    int xq = (quad + ((l16 >> 1) & 3)) & 3;

    f32x4 acc[2][2] = {};

    // prologue: stage K-step 0 (k=0..63) into buf0: A 2 ops (subs), B 2 ops (stagers)
    gl_lds16(Ag,      lA);
    gl_lds16(Ag + 32, lA + 4096);
    if (stager) {
        gl_lds16(Bg,      lB);
        gl_lds16(Bg + 32, lB + 2048);
    }

    for (int it = 0; it < NT; ++it) {
        const int cur = it & 1, nxt = cur ^ 1;
        if (it + 1 < NT) {
            const int k0n = (it + 1) * 64;
            gl_lds16(Ag + k0n,      lA + nxt * 8192);
            gl_lds16(Ag + k0n + 32, lA + nxt * 8192 + 4096);
            if (stager) {
                gl_lds16(Bg + k0n,      lB + nxt * 4096);
                gl_lds16(Bg + k0n + 32, lB + nxt * 4096 + 2048);
                asm volatile("s_waitcnt vmcnt(4)" ::: "memory");  // cur's 4 done
            } else {
                asm volatile("s_waitcnt vmcnt(2)" ::: "memory");  // cur's 2 done
            }
        } else {
            asm volatile("s_waitcnt vmcnt(0)" ::: "memory");
        }
        __builtin_amdgcn_s_barrier();
        asm volatile("" ::: "memory");

        const unsigned short* bA = sA + cur * 8192;
        const unsigned short* bB = sB + cur * 4096;

#pragma unroll
        for (int s = 0; s < 2; s++) {
            bf16x8 a[2], bfr[2];
#pragma unroll
            for (int i = 0; i < 2; i++)
                a[i] = *(const bf16x8*)(bA + s * 4096 + (wr + i * 16 + l16) * 32 + xq * 8);
#pragma unroll
            for (int j = 0; j < 2; j++)
                bfr[j] = *(const bf16x8*)(bB + s * 2048 + (wc + j * 16 + l16) * 32 + xq * 8);
#pragma unroll
            for (int i = 0; i < 2; i++)
#pragma unroll
                for (int j = 0; j < 2; j++)
                    acc[i][j] = __builtin_amdgcn_mfma_f32_16x16x32_bf16(a[i], bfr[j], acc[i][j], 0, 0, 0);
        }
        asm volatile("" ::: "memory");
        __builtin_amdgcn_s_barrier();
        asm volatile("" ::: "memory");
    }

#pragma unroll
    for (int j = 0; j < 2; j++) {
        int col = col0 + wc + j * 16 + l16;
        float bv = bias[col];
#pragma unroll
        for (int i = 0; i < 2; i++) {
            int rbase = row0 + wr + i * 16 + quad * 4;
#pragma unroll
            for (int r = 0; r < 4; r++)
                C[(size_t)(rbase + r) * ldc + col] = acc[i][j][r] + bv;
        }
    }
}

// ---------- launch ----------
extern "C" void kernel_launch(void* const* d_in, const int* in_sizes, int n_in,
                              void* d_out, int out_size, void* d_ws, size_t ws_size,
                              hipStream_t stream) {
    const float* x   = (const float*)d_in[0];
    const float* W1  = (const float*)d_in[1];
    const float* b1  = (const float*)d_in[2];
    const float* W2  = (const float*)d_in[3];
    const float* b2f = (const float*)d_in[4];
    float* out = (float*)d_out;

    unsigned short* ws    = (unsigned short*)d_ws;
    unsigned short* xb    = ws;                                 // 11520*512
    unsigned short* h_blk = xb + (size_t)M_ROWS * D_IN;         // 11520*2080 (CPAD layout)
    unsigned short* uf    = h_blk + (size_t)M_ROWS * K2;        // 11520*2112
    unsigned short* w1t   = uf + (size_t)M_ROWS * K2P;          // 2048*512
    unsigned short* w2t   = w1t + (size_t)HDP * D_IN;           // 512*2112

    // 1. prep: conv x, pack W1t, pack W2t (one dispatch)
    hipLaunchKernelGGL(prep, dim3(7776), dim3(256), 0, stream, x, W1, W2, xb, w1t, w2t);

    // 2. GEMM1 -> h_blk (8 waves, BK=64, 8 steps, 1440 blocks, XCD-swizzled)
    hipLaunchKernelGGL(gemm1_blk, dim3((M_ROWS / 128) * (HDP / 128)), dim3(512), 0, stream,
                       xb, w1t, b1, h_blk);

    // 3. fused fold + normalize + relu + unfold -> uf (stride K2P, tails zeroed)
    hipLaunchKernelGGL(fold_unfold, dim3(B2C * CCH * 2), dim3(256), 0, stream, h_blk, uf);

    // 4. GEMM2 -> out (f32, 128x64 tiles, 720 blocks, 8 waves, BK=64, 33 steps)
    hipLaunchKernelGGL(gemm2, dim3((M_ROWS / 128) * (D_IN / 64)), dim3(512), 0, stream,
                       uf, w2t, b2f, out);
}

// Round 12
// 183.478 us; speedup vs baseline: 1.1064x; 1.1064x over previous
//
#include <hip/hip_runtime.h>
#include <hip/hip_bf16.h>

// ---------- constants ----------
#define M_ROWS   11520          // b*n = 2*5760
#define D_IN     512
#define HD       1960
#define HDP      2048           // padded N for GEMM1 tiles
#define CPAD     52             // per-cch padded patch count (49 -> 52)
#define K2       2080           // 40*52, GEMM2 logical K
#define K2P      2112           // K2 padded to 64 (BK=64 -> 33 steps); tails zeroed
#define B2C      16
#define NVECS    720            // 20*36
#define LH       20
#define LW       36
#define HH       60
#define WW       108
#define CCH      40             // 1960/49

using bf16x8 = __attribute__((ext_vector_type(8))) short;
using f32x4  = __attribute__((ext_vector_type(4))) float;
using f4     = __attribute__((ext_vector_type(4))) float;
using su4    = __attribute__((ext_vector_type(4))) unsigned short;

__device__ __forceinline__ float bf2f(unsigned short u) {
    unsigned int x = ((unsigned int)u) << 16;
    return __builtin_bit_cast(float, x);
}
__device__ __forceinline__ unsigned short f2bf(float f) {
    unsigned int x = __builtin_bit_cast(unsigned int, f);
    unsigned int r = (x + 0x7fffu + ((x >> 16) & 1u)) >> 16;
    return (unsigned short)r;
}

// async global->LDS, 16 bytes per lane (global_load_lds_dwordx4)
__device__ __forceinline__ void gl_lds16(const unsigned short* g, unsigned short* l) {
    __builtin_amdgcn_global_load_lds(
        (const __attribute__((address_space(1))) unsigned int*)g,
        (__attribute__((address_space(3))) unsigned int*)l, 16, 0, 0);
}

// ---------- prep: conv x -> bf16 | pack W1t | pack W2t (52-relabel, K2P stride) ----------
__global__ __launch_bounds__(256) void prep(
    const float* __restrict__ x, const float* __restrict__ W1, const float* __restrict__ W2,
    unsigned short* __restrict__ xb, unsigned short* __restrict__ w1t,
    unsigned short* __restrict__ w2t)
{
    __shared__ unsigned short tile[32][33];
    int b = blockIdx.x, t = threadIdx.x;
    if (b < 5760) {                               // x (f32) -> xb (bf16), 4/thread
        int i = b * 256 + t;
        f4 v = ((const f4*)x)[i];
        su4 o;
        o.x = f2bf(v.x); o.y = f2bf(v.y); o.z = f2bf(v.z); o.w = f2bf(v.w);
        ((su4*)xb)[i] = o;
        return;
    }
    int tx = t & 31, ty = t >> 5;                 // ty in [0,8)
    if (b < 6784) {                               // W1t[n*512+k] = W1[k*1960+n]
        int blk = b - 5760;
        int kt = blk & 15, nt = blk >> 4;
        int k0 = kt * 32, n0 = nt * 32;
#pragma unroll
        for (int p = 0; p < 4; p++) {
            int k = k0 + ty + p * 8;
            int n = n0 + tx;
            tile[ty + p * 8][tx] = (n < HD) ? f2bf(W1[k * HD + n]) : (unsigned short)0;
        }
        __syncthreads();
#pragma unroll
        for (int p = 0; p < 4; p++) {
            int n = n0 + ty + p * 8;
            int k = k0 + tx;
            w1t[n * 512 + k] = tile[tx][ty + p * 8];
        }
    } else {                                      // W2t[n*K2P + cch*52+kk] = W2[(cch*49+kk)*512+n]
        int blk = b - 6784;                       // 62 kt x 16 nt
        int kt = blk % 62, nt = blk / 62;
        int k0 = kt * 32, n0 = nt * 32;
        if (kt == 0) {                            // zero 52-pad holes + K2P tail once per n-tile
            for (int i = t; i < 32 * CCH * 3; i += 256) {
                int nn = n0 + (i & 31);
                int cc = (i >> 5) / 3, p = (i >> 5) % 3;
                w2t[nn * K2P + cc * CPAD + 49 + p] = 0;
            }
            if (t < 256) {                        // 32 rows x 8 su4 = 256: tail [2080,2112)
                su4 z = {};
                int nn = n0 + (t >> 3), e = t & 7;
                *(su4*)(w2t + (size_t)nn * K2P + 2080 + e * 4) = z;
            }
        }
#pragma unroll
        for (int p = 0; p < 4; p++) {
            int k = k0 + ty + p * 8;
            int n = n0 + tx;
            tile[ty + p * 8][tx] = (k < HD) ? f2bf(W2[k * 512 + n]) : (unsigned short)0;
        }
        __syncthreads();
#pragma unroll
        for (int p = 0; p < 4; p++) {
            int n = n0 + ty + p * 8;
            int k = k0 + tx;
            if (k < HD) {
                int cch = k / 49, kk = k - cch * 49;
                w2t[n * K2P + cch * CPAD + kk] = tile[tx][ty + p * 8];
            }
        }
    }
}

// ---------- GEMM1: BK=64 (two 32-col sub-tiles), 8 waves, 128x128, 1440 blocks ----------
__global__ __launch_bounds__(512) void gemm1_blk(
    const unsigned short* __restrict__ A,
    const unsigned short* __restrict__ Bt,
    const float* __restrict__ bias,
    unsigned short* __restrict__ h_blk)
{
    __shared__ unsigned short sA[2 * 2 * 128 * 32];   // 2 buf x 2 sub x 8KB = 32KB
    __shared__ unsigned short sB[2 * 2 * 128 * 32];   // 32KB (64KB total)
    const int lda = D_IN, ldb = D_IN;
    const int NT = D_IN / 64;                     // 8 K-steps of 64

    int g = (blockIdx.x & 7) * 180 + (blockIdx.x >> 3);   // 1440 blocks, chunk=180
    int bx = g & 15, by = g >> 4;
    int t    = threadIdx.x;                       // 0..511
    int w    = t >> 6;                            // 0..7
    int lane = t & 63;
    int quad = lane >> 4;
    int l16  = lane & 15;
    int row0 = by * 128, col0 = bx * 128;
    int wr = (w >> 2) * 64;                       // 0 or 64
    int wc = (w & 3) * 32;                        // 0,32,64,96

    int srow = t >> 2;                            // 0..127
    int qb = ((t & 3) - ((srow >> 1) & 3)) & 3;   // global 16B-block this thread stages
    const unsigned short* Ag = A  + (size_t)(row0 + srow) * lda + qb * 8;
    const unsigned short* Bg = Bt + (size_t)(col0 + srow) * ldb + qb * 8;
    unsigned short* lA = sA + t * 8;              // + buf*8192 + sub*4096
    unsigned short* lB = sB + t * 8;

    int xq = (quad + ((l16 >> 1) & 3)) & 3;       // swizzled read slot

    f32x4 acc[4][2] = {};

    // prologue: stage K-step 0 (k=0..63) into buf0 (4 ops/thread)
    gl_lds16(Ag,      lA);
    gl_lds16(Ag + 32, lA + 4096);
    gl_lds16(Bg,      lB);
    gl_lds16(Bg + 32, lB + 4096);

#pragma unroll
    for (int it = 0; it < NT; ++it) {
        const int cur = it & 1, nxt = cur ^ 1;
        if (it + 1 < NT) {
            const int k0n = (it + 1) * 64;
            gl_lds16(Ag + k0n,      lA + nxt * 8192);
            gl_lds16(Ag + k0n + 32, lA + nxt * 8192 + 4096);
            gl_lds16(Bg + k0n,      lB + nxt * 8192);
            gl_lds16(Bg + k0n + 32, lB + nxt * 8192 + 4096);
            asm volatile("s_waitcnt vmcnt(4)" ::: "memory");  // cur's 4 done; nxt's 4 in flight
        } else {
            asm volatile("s_waitcnt vmcnt(0)" ::: "memory");
        }
        __builtin_amdgcn_s_barrier();             // all waves: cur staged
        asm volatile("" ::: "memory");            // no LDS reads hoisted above barrier

        const unsigned short* bA = sA + cur * 8192;
        const unsigned short* bB = sB + cur * 8192;

#pragma unroll
        for (int s = 0; s < 2; s++) {
            bf16x8 a[4], bfr[2];
#pragma unroll
            for (int i = 0; i < 4; i++)
                a[i] = *(const bf16x8*)(bA + s * 4096 + (wr + i * 16 + l16) * 32 + xq * 8);
#pragma unroll
            for (int j = 0; j < 2; j++)
                bfr[j] = *(const bf16x8*)(bB + s * 4096 + (wc + j * 16 + l16) * 32 + xq * 8);
#pragma unroll
            for (int i = 0; i < 4; i++)
#pragma unroll
                for (int j = 0; j < 2; j++)
                    acc[i][j] = __builtin_amdgcn_mfma_f32_16x16x32_bf16(a[i], bfr[j], acc[i][j], 0, 0, 0);
        }
        asm volatile("" ::: "memory");
        __builtin_amdgcn_s_barrier();             // all waves done reading cur
        asm volatile("" ::: "memory");
    }

    // row terms: addr = b2*1497600 + cch*37440 + sp*52 + kk
    int rowterm[16];
#pragma unroll
    for (int i = 0; i < 4; i++)
#pragma unroll
        for (int r = 0; r < 4; r++) {
            int row = row0 + wr + i * 16 + quad * 4 + r;
            int bb = row / NVECS;
            int sp = row - bb * NVECS;
            rowterm[i * 4 + r] = bb * (CCH * NVECS * CPAD) + sp * CPAD;
        }

#pragma unroll
    for (int j = 0; j < 2; j++) {
        int col = col0 + wc + j * 16 + l16;       // natural: col = cch*49 + kk
        if (col < HD) {
            int cch = col / 49, kk = col - cch * 49;
            int colterm = cch * (NVECS * CPAD) + kk;
            float bv = bias[col];
#pragma unroll
            for (int i = 0; i < 4; i++)
#pragma unroll
                for (int r = 0; r < 4; r++)
                    h_blk[(size_t)rowterm[i * 4 + r] + colterm] = f2bf(acc[i][j][r] + bv);
        }
    }

    // zero pad holes (kk=49..51) of every cch-row this tile covers -> dense sectors
    int cch0 = col0 / 49;
    int cch1 = (col0 + 127) / 49; if (cch1 > CCH - 1) cch1 = CCH - 1;
    int ncch = cch1 - cch0 + 1;
    if (wc == 0 && l16 < 3 * ncch) {
        int c = l16 / 3, p = l16 - c * 3;
        int padcol = (cch0 + c) * (NVECS * CPAD) + 49 + p;
#pragma unroll
        for (int i = 0; i < 4; i++)
#pragma unroll
            for (int r = 0; r < 4; r++)
                h_blk[(size_t)rowterm[i * 4 + r] + padcol] = 0;
    }
}

// ---------- fold+norm+relu+unfold: 512 threads, async staging ----------
// R11 post-mortem: fold top at 43.4us; VALUBusy 40%, HBM 25%, Occ 22% -> phase
// work-bound with only 216/247 active lanes per phase and 4 waves/block.
// v2: 512 threads halve each phase's per-lane trip count; staging via gl_lds16
// (contiguous 44.9KB copy, per-lane dest = base+lane*16 matches HW). Partial
// staging iter (256 chunks) is wave-aligned (waves fully active or idle).
// LDS 45056+7128=52184B -> 3 blocks/CU, 24 waves/CU.
__global__ __launch_bounds__(512) void fold_unfold(
    const unsigned short* __restrict__ h_blk,
    unsigned short* __restrict__ uf)
{
    __shared__ unsigned short h_lds[22528];           // 45,056 B (44,928 used +128 pad)
    __shared__ unsigned short y_lds[33 * WW];         //  7,128 B
    int bid  = blockIdx.x;                            // 16*40*2 = 1280
    int half = bid & 1;
    int cch  = (bid >> 1) % CCH;
    int b2   = bid / (CCH * 2);
    int tid  = threadIdx.x;

    int lh_base = half ? 8 : 0;
    int y0 = half ? 27 : 0;
    int ny = half ? 33 : 31;

    // ---- async stage h slice (2816 x 16B chunks; last overreads 128B into pad) ----
    const unsigned short* hsrc = h_blk +
        ((size_t)(b2 * CCH + cch) * NVECS + lh_base * 36) * CPAD;
    for (int i = tid; i < 2816; i += 512)
        gl_lds16(hsrc + i * 8, h_lds + i * 8);
    asm volatile("s_waitcnt vmcnt(0)" ::: "memory");
    __syncthreads();

    // ---- fold+norm+relu: thread owns column c; rows strided by 4 ----
    if (tid < 432) {
        int c  = tid % 108;
        int rr = tid / 108;                       // 0..3
        int cp  = c + 3;
        int q2  = cp / 3, rem2 = cp - q2 * 3;
        bool cv0 = (q2 <= 35);
        bool cv2 = (rem2 == 0) & (q2 >= 2);
        int n2  = 1 + (int)cv0 + (int)cv2;
        float rn2 = (n2 == 3) ? (1.0f / 3.0f) : (n2 == 2 ? 0.5f : 1.0f);
        int ca0 = q2 * CPAD + rem2;               // lw0 col offset (valid iff cv0)
        int ca1 = (q2 - 1) * CPAD + rem2 + 3;     // lw1 (always valid)
        int ca2 = (q2 - 2) * CPAD + rem2 + 6;     // lw2 (valid iff cv2)
        for (; rr < ny; rr += 4) {
            int r  = y0 + rr;
            int rp = r + 3;
            int q1 = rp / 3, rem1 = rp - q1 * 3;
            bool rv0 = (q1 <= 19);
            bool rv2 = (rem1 == 0) & (q1 >= 2);
            int n1 = 1 + (int)rv0 + (int)rv2;
            float rn1 = (n1 == 3) ? (1.0f / 3.0f) : (n1 == 2 ? 0.5f : 1.0f);
            int ra0 = (q1 - lh_base) * (36 * CPAD) + rem1 * 7;   // sl0 row base
            int ra1 = ra0 - 36 * CPAD + 21;                      // sl1
            int ra2 = ra0 - 2 * (36 * CPAD) + 42;                // sl2
            float s = 0.0f;
#define FT(vr, ra, vc, ca) {                                   \
            bool vv = (vr) & (vc);                             \
            int ad = vv ? ((ra) + (ca)) : 0;                   \
            float val = bf2f(h_lds[ad]);                       \
            s += vv ? val : 0.0f; }
            FT(rv0,  ra0, cv0,  ca0)
            FT(rv0,  ra0, true, ca1)
            FT(rv0,  ra0, cv2,  ca2)
            FT(true, ra1, cv0,  ca0)
            FT(true, ra1, true, ca1)
            FT(true, ra1, cv2,  ca2)
            FT(rv2,  ra2, cv0,  ca0)
            FT(rv2,  ra2, true, ca1)
            FT(rv2,  ra2, cv2,  ca2)
#undef FT
            y_lds[rr * WW + c] = f2bf(fmaxf(s * rn1 * rn2, 0.0f));
        }
    }
    __syncthreads();

    // ---- unfold: thread owns quad q (j0=4q); rows strided by 38 ----
    if (tid < 494) {
        int q  = tid % 13;
        int ri = tid / 13;                        // 0..37
        int j0 = q * 4;
        int lh0 = 10 * half;
        int k1c[4], k2c[4];
        bool jv[4];
#pragma unroll
        for (int e = 0; e < 4; e++) {
            int j = j0 + e;
            jv[e] = (j < 49);
            int k1 = j / 7;
            k1c[e] = k1;
            k2c[e] = j - k1 * 7;
        }
        int lh = lh0 + ri / 36, lw = ri % 36;     // ri < 38
        for (int rcur = ri; rcur < 360; rcur += 38) {
            int rb = 3 * lh - 3, cb = 3 * lw - 3;
            su4 o;
#pragma unroll
            for (int e = 0; e < 4; e++) {
                unsigned short val = 0;
                if (jv[e]) {
                    int r = rb + k1c[e], cc = cb + k2c[e];
                    if ((unsigned)r < (unsigned)HH && (unsigned)cc < (unsigned)WW)
                        val = y_lds[(r - y0) * WW + cc];
                }
                ((unsigned short*)&o)[e] = val;
            }
            int row = b2 * NVECS + lh * 36 + lw;
            *(su4*)(uf + (size_t)row * K2P + cch * CPAD + j0) = o;
            lw += 2; lh += 1;
            if (lw >= 36) { lw -= 36; lh++; }
        }
    }

    // ---- zero uf K2P tail [2080,2112) for this (b2,half)'s 360 rows (cch==0 blocks) ----
    if (cch == 0) {
        su4 z = {};
        size_t base = (size_t)(b2 * NVECS + (10 * half) * 36) * K2P + 2080;
        for (int i = tid; i < 360 * 8; i += 512) {
            int rr = i >> 3, e = i & 7;
            *(su4*)(uf + base + (size_t)rr * K2P + e * 4) = z;
        }
    }
}

// ---------- GEMM2: BK=64 (two 32-col sub-tiles), 8 waves, 128x64, 720 blocks ----------
__global__ __launch_bounds__(512) void gemm2(
    const unsigned short* __restrict__ A,
    const unsigned short* __restrict__ Bt,
    const float* __restrict__ bias,
    float* __restrict__ C)
{
    __shared__ unsigned short sA[2 * 2 * 128 * 32];   // 2 buf x 2 sub x 8KB = 32KB
    __shared__ unsigned short sB[2 * 2 * 64 * 32];    // 2 buf x 2 sub x 4KB = 16KB
    const int lda = K2P, ldb = K2P, ldc = D_IN;
    const int NT = K2P / 64;                      // 33 K-steps of 64

    int g = (blockIdx.x & 7) * 90 + (blockIdx.x >> 3);    // 720 blocks, chunk=90
    int bx = g & 7, by = g >> 3;                          // 8 col-tiles of 64, 90 row-tiles
    int t    = threadIdx.x;                       // 0..511
    int w    = t >> 6;                            // 0..7
    int lane = t & 63;
    int quad = lane >> 4;
    int l16  = lane & 15;
    int row0 = by * 128, col0 = bx * 64;
    int wr = (w >> 1) * 32;                       // 0,32,64,96
    int wc = (w & 1) * 32;                        // 0,32

    bool stager = (t < 256);                      // B stagers (wave-uniform)
    int srow  = t >> 2;                           // 0..127 (A rows)
    int srowB = srow & 63;                        // 0..63  (B rows, t<256 only)
    int qb  = ((t & 3) - ((srow  >> 1) & 3)) & 3;
    int qbB = ((t & 3) - ((srowB >> 1) & 3)) & 3;
    const unsigned short* Ag = A  + (size_t)(row0 + srow)  * lda + qb  * 8;
    const unsigned short* Bg = Bt + (size_t)(col0 + srowB) * ldb + qbB * 8;
    unsigned short* lA = sA + t * 8;              // + buf*8192 + sub*4096
    unsigned short* lB = sB + t * 8;              // + buf*4096 + sub*2048 (t<256)

    int xq = (quad + ((l16 >> 1) & 3)) & 3;

    f32x4 acc[2][2] = {};

    // prologue: stage K-step 0 (k=0..63) into buf0: A 2 ops (subs), B 2 ops (stagers)
    gl_lds16(Ag,      lA);
    gl_lds16(Ag + 32, lA + 4096);
    if (stager) {
        gl_lds16(Bg,      lB);
        gl_lds16(Bg + 32, lB + 2048);
    }

    for (int it = 0; it < NT; ++it) {
        const int cur = it & 1, nxt = cur ^ 1;
        if (it + 1 < NT) {
            const int k0n = (it + 1) * 64;
            gl_lds16(Ag + k0n,      lA + nxt * 8192);
            gl_lds16(Ag + k0n + 32, lA + nxt * 8192 + 4096);
            if (stager) {
                gl_lds16(Bg + k0n,      lB + nxt * 4096);
                gl_lds16(Bg + k0n + 32, lB + nxt * 4096 + 2048);
                asm volatile("s_waitcnt vmcnt(4)" ::: "memory");  // cur's 4 done
            } else {
                asm volatile("s_waitcnt vmcnt(2)" ::: "memory");  // cur's 2 done
            }
        } else {
            asm volatile("s_waitcnt vmcnt(0)" ::: "memory");
        }
        __builtin_amdgcn_s_barrier();
        asm volatile("" ::: "memory");

        const unsigned short* bA = sA + cur * 8192;
        const unsigned short* bB = sB + cur * 4096;

#pragma unroll
        for (int s = 0; s < 2; s++) {
            bf16x8 a[2], bfr[2];
#pragma unroll
            for (int i = 0; i < 2; i++)
                a[i] = *(const bf16x8*)(bA + s * 4096 + (wr + i * 16 + l16) * 32 + xq * 8);
#pragma unroll
            for (int j = 0; j < 2; j++)
                bfr[j] = *(const bf16x8*)(bB + s * 2048 + (wc + j * 16 + l16) * 32 + xq * 8);
#pragma unroll
            for (int i = 0; i < 2; i++)
#pragma unroll
                for (int j = 0; j < 2; j++)
                    acc[i][j] = __builtin_amdgcn_mfma_f32_16x16x32_bf16(a[i], bfr[j], acc[i][j], 0, 0, 0);
        }
        asm volatile("" ::: "memory");
        __builtin_amdgcn_s_barrier();
        asm volatile("" ::: "memory");
    }

#pragma unroll
    for (int j = 0; j < 2; j++) {
        int col = col0 + wc + j * 16 + l16;
        float bv = bias[col];
#pragma unroll
        for (int i = 0; i < 2; i++) {
            int rbase = row0 + wr + i * 16 + quad * 4;
#pragma unroll
            for (int r = 0; r < 4; r++)
                C[(size_t)(rbase + r) * ldc + col] = acc[i][j][r] + bv;
        }
    }
}

// ---------- launch ----------
extern "C" void kernel_launch(void* const* d_in, const int* in_sizes, int n_in,
                              void* d_out, int out_size, void* d_ws, size_t ws_size,
                              hipStream_t stream) {
    const float* x   = (const float*)d_in[0];
    const float* W1  = (const float*)d_in[1];
    const float* b1  = (const float*)d_in[2];
    const float* W2  = (const float*)d_in[3];
    const float* b2f = (const float*)d_in[4];
    float* out = (float*)d_out;

    unsigned short* ws    = (unsigned short*)d_ws;
    unsigned short* xb    = ws;                                 // 11520*512
    unsigned short* h_blk = xb + (size_t)M_ROWS * D_IN;         // 11520*2080 (CPAD layout)
    unsigned short* uf    = h_blk + (size_t)M_ROWS * K2;        // 11520*2112
    unsigned short* w1t   = uf + (size_t)M_ROWS * K2P;          // 2048*512
    unsigned short* w2t   = w1t + (size_t)HDP * D_IN;           // 512*2112

    // 1. prep: conv x, pack W1t, pack W2t (one dispatch)
    hipLaunchKernelGGL(prep, dim3(7776), dim3(256), 0, stream, x, W1, W2, xb, w1t, w2t);

    // 2. GEMM1 -> h_blk (8 waves, BK=64, 8 steps, 1440 blocks, XCD-swizzled)
    hipLaunchKernelGGL(gemm1_blk, dim3((M_ROWS / 128) * (HDP / 128)), dim3(512), 0, stream,
                       xb, w1t, b1, h_blk);

    // 3. fused fold + normalize + relu + unfold -> uf (512 thr, async staging)
    hipLaunchKernelGGL(fold_unfold, dim3(B2C * CCH * 2), dim3(512), 0, stream, h_blk, uf);

    // 4. GEMM2 -> out (f32, 128x64 tiles, 720 blocks, 8 waves, BK=64, 33 steps)
    hipLaunchKernelGGL(gemm2, dim3((M_ROWS / 128) * (D_IN / 64)), dim3(512), 0, stream,
                       uf, w2t, b2f, out);
}